// Round 15
// baseline (605.973 us; speedup 1.0000x reference)
//
#include <hip/hip_runtime.h>
#include <cstddef>

#define Cc 96
#define CH 384
#define Mtok 262144   // B*H*W = 16*128*128
#define Mi   16384    // tokens per image

typedef unsigned short us8 __attribute__((ext_vector_type(8)));
typedef float f8 __attribute__((ext_vector_type(8)));
typedef short s8v __attribute__((ext_vector_type(8)));
typedef float f4v __attribute__((ext_vector_type(4)));

static __device__ __forceinline__ float b2f(unsigned short s){
  union { unsigned u; float f; } v; v.u = ((unsigned)s) << 16; return v.f;
}
static __device__ __forceinline__ unsigned short f2b(float f){
  union { float f; unsigned u; } v; v.f = f;
  unsigned r = v.u + 0x7fffu + ((v.u >> 16) & 1u);
  return (unsigned short)(r >> 16);
}

// ---------------- K0a: transpose dw_w [c][tap] -> wt_t [tap][c] ----------------
__global__ __launch_bounds__(64) void k_wprep(const float* __restrict__ dww,
    float* __restrict__ wt_t){
  int i = blockIdx.x*64 + threadIdx.x;   // i = tap*CH + c
  if (i < 9*CH){
    int tap = i / CH, c = i - tap*CH;
    wt_t[i] = dww[c*9 + tap];
  }
}

// ---------------- K0b: pack fc2_w [384][96] f32 -> bf16 MFMA b-frag layout ----
__global__ __launch_bounds__(256) void k_wprep2(const float* __restrict__ fc2w,
    unsigned short* __restrict__ Bp){
  int i = blockIdx.x*256 + threadIdx.x;   // < 6*12*64*8 = 36864
  int j = i & 7;
  int t = i >> 3;
  int l = t & 63;
  int u = t >> 6;          // 0..71
  int ks = u % 12, nt = u / 12;
  int k   = ks*32 + (l>>4)*8 + j;
  int col = nt*16 + (l&15);
  Bp[i] = f2b(fc2w[(size_t)k*96 + col]);
}

// ---------------- K0c: pack fc1_w [96][384] f32 -> bf16 MFMA b-frag layout ----
__global__ __launch_bounds__(256) void k_wprep1(const float* __restrict__ fc1w,
    unsigned short* __restrict__ Bp1){
  int i = blockIdx.x*256 + threadIdx.x;   // < 24*3*64*8 = 36864
  int j = i & 7;
  int t = i >> 3;
  int l = t & 63;
  int u = t >> 6;          // 0..71
  int ks = u % 3, nt = u / 3;
  int k   = ks*32 + (l>>4)*8 + j;
  int col = nt*16 + (l&15);
  Bp1[i] = f2b(fc1w[(size_t)k*CH + col]);
}

// ---------------- K2: FUSED fc1 GEMM (MFMA) + gate-H + H-shift blend -> hid ---
// Block = 320 thr (5 waves) covers 64 interior tokens (16 h-rows x 4 w-cols).
// Computes y1 for 80 tile-tokens (20 rows incl +-2 halo) via MFMA, keeps y1 in
// LDS (bf16, same rounding as the old global y1), blends in-LDS, writes hid.
// Kills the 402 MB y1 global round-trip of the separate k_blend_h.
__global__ __launch_bounds__(320) void k_fc1f(const float* __restrict__ x,
    const float* __restrict__ gh_w, const float* __restrict__ gh_b,
    const unsigned short* __restrict__ Bp1, const float* __restrict__ fc1b,
    unsigned short* __restrict__ hid, int base, int Mloc){
  __shared__ union SU {
    unsigned short A[80][100];    // phase 1-2: bf16 A-tile (16 KB)
    unsigned short Y[80][392];    // phase 3-4: bf16 y1 tile (62.7 KB)
  } S;
  __shared__ float wh_s[80][5];
  const int tid = threadIdx.x;
  const int bid = (int)blockIdx.x;
  const int img  = bid >> 8;           // 256 blocks per image
  const int rem  = bid & 255;
  const int band = rem >> 5;           // 16-row band 0..7
  const int colg = rem & 31;           // 4-col group 0..31
  const int h0 = band*16;
  const int w0 = colg*4;
  const size_t lbase = (size_t)img*16384;       // token base within chunk

  // Phase 1: stage A (80 tile-tokens; halo rows outside image -> zeros) + gate-H
  {
    const int sr = tid>>2, sq = tid&3;   // sr = tile token 0..79
    const int r = sr>>2, cw = sr&3;
    const int h = h0 + r - 2;
    const bool valid = ((unsigned)h < 128u);
    float part[5] = {0.f,0.f,0.f,0.f,0.f};
    if (valid){
      const float* src = &x[((size_t)base + lbase + h*128 + w0 + cw)*Cc + sq*24];
      #pragma unroll
      for (int p=0;p<3;++p){
        float4 v0 = *(const float4*)&src[p*8];
        float4 v1 = *(const float4*)&src[p*8+4];
        us8 ov;
        ov[0]=f2b(v0.x); ov[1]=f2b(v0.y); ov[2]=f2b(v0.z); ov[3]=f2b(v0.w);
        ov[4]=f2b(v1.x); ov[5]=f2b(v1.y); ov[6]=f2b(v1.z); ov[7]=f2b(v1.w);
        *(us8*)&S.A[sr][sq*24 + p*8] = ov;
        #pragma unroll
        for (int s=0;s<5;++s){
          float4 g0 = *(const float4*)&gh_w[s*Cc + sq*24 + p*8];
          float4 g1 = *(const float4*)&gh_w[s*Cc + sq*24 + p*8 + 4];
          part[s]=fmaf(v0.x,g0.x,part[s]); part[s]=fmaf(v0.y,g0.y,part[s]);
          part[s]=fmaf(v0.z,g0.z,part[s]); part[s]=fmaf(v0.w,g0.w,part[s]);
          part[s]=fmaf(v1.x,g1.x,part[s]); part[s]=fmaf(v1.y,g1.y,part[s]);
          part[s]=fmaf(v1.z,g1.z,part[s]); part[s]=fmaf(v1.w,g1.w,part[s]);
        }
      }
    } else {
      us8 z = {0,0,0,0,0,0,0,0};
      #pragma unroll
      for (int p=0;p<3;++p) *(us8*)&S.A[sr][sq*24 + p*8] = z;
    }
    #pragma unroll
    for (int s=0;s<5;++s){
      float v = part[s];
      v += __shfl_xor(v, 1, 64);
      v += __shfl_xor(v, 2, 64);
      part[s] = v;
    }
    if (sq==0 && valid){
      float l[5];
      #pragma unroll
      for (int s=0;s<5;++s) l[s] = part[s] + gh_b[s];
      float mx = fmaxf(fmaxf(fmaxf(l[0],l[1]),fmaxf(l[2],l[3])),l[4]);
      float sum=0.f;
      #pragma unroll
      for (int s=0;s<5;++s){ l[s]=__expf(l[s]-mx); sum+=l[s]; }
      float inv=1.f/sum;
      #pragma unroll
      for (int s=0;s<5;++s) wh_s[sr][s] = l[s]*inv;
    }
  }
  __syncthreads();

  // Phase 2: MFMA — wave wv computes tile-token rows [wv*16, wv*16+16)
  const int wv = tid>>6, l = tid&63;
  const int row16 = l&15, g = l>>4;
  f4v acc[24];
  #pragma unroll
  for (int nt=0;nt<24;++nt) acc[nt] = (f4v){0.f,0.f,0.f,0.f};
  #pragma unroll
  for (int ks=0;ks<3;++ks){
    s8v a = *(const s8v*)&S.A[wv*16 + row16][ks*32 + g*8];
    #pragma unroll
    for (int nt=0;nt<24;++nt){
      s8v b = *(const s8v*)&Bp1[((size_t)(nt*3+ks)*64 + l)*8];
      acc[nt] = __builtin_amdgcn_mfma_f32_16x16x32_bf16(a, b, acc[nt], 0, 0, 0);
    }
  }
  __syncthreads();   // all A reads done before Y overwrites the union

  // Phase 3: write y1 tile (bf16) to LDS
  #pragma unroll
  for (int nt=0;nt<24;++nt){
    #pragma unroll
    for (int r=0;r<4;++r){
      S.Y[wv*16 + g*4 + r][nt*16 + row16] = f2b(acc[nt][r]);
    }
  }
  __syncthreads();

  // Phase 4: H-shift blend from LDS, write hid (first 256 threads)
  if (tid < 256){
    const int tl = tid>>2, q = tid&3;   // interior token 0..63, 96-ch quarter
    const int rr = 2 + (tl>>2);         // tile row 2..17
    const int cw = tl&3;
    const int it = rr*4 + cw;           // tile token index
    const int h  = h0 + (tl>>2);
    float swgt[5];
    #pragma unroll
    for (int i=0;i<5;++i){
      int h2 = h - (i-2);
      swgt[i] = ((unsigned)h2 < 128u) ? wh_s[it][i] : 0.f;
    }
    unsigned short* o = &hid[(lbase + h*128 + w0 + cw)*CH];
    #pragma unroll
    for (int cc=0;cc<4;++cc){
      const int c0 = q*96 + cc*24;
      float acc2[24];
      #pragma unroll
      for (int j=0;j<24;++j) acc2[j] = fc1b[c0+j];
      #pragma unroll
      for (int i=0;i<5;++i){
        if (swgt[i] != 0.f){
          const unsigned short* yr = &S.Y[it - 4*(i-2)][c0];
          #pragma unroll
          for (int p=0;p<3;++p){
            us8 v = *(const us8*)&yr[p*8];
            #pragma unroll
            for (int j=0;j<8;++j) acc2[p*8+j] = fmaf(swgt[i], b2f(v[j]), acc2[p*8+j]);
          }
        }
      }
      #pragma unroll
      for (int p=0;p<3;++p){
        us8 ov;
        #pragma unroll
        for (int j=0;j<8;++j) ov[j] = f2b(acc2[p*8+j]);
        *(us8*)&o[c0 + p*8] = ov;
      }
    }
  }
}

// ---------------- K3: dwconv3x3 + bias + fast GELU + gate-W -> hid2, ww -------
// 256 thr = 32 token-PAIRS x 8 ch-groups (2 tokens/thread), halo-shared loads.
__global__ __launch_bounds__(256) void k_dw(const unsigned short* __restrict__ hid,
    const float* __restrict__ wt_t, const float* __restrict__ dwb,
    const float* __restrict__ gww, const float* __restrict__ gwb,
    unsigned short* __restrict__ hid2, float* __restrict__ ww, int Mloc){
  const int tid = threadIdx.x;
  const int m0 = blockIdx.x*64;
  const int p  = tid>>3, cg = tid&7;
  const int m  = m0 + 2*p;                // tokens m, m+1 (same h row)
  const int h = (m>>7)&127, w = m&127;
  bool hok[3];
  #pragma unroll
  for (int k=0;k<3;++k) hok[k] = ((unsigned)(h+k-1) < 128u);
  bool c0ok = (w > 0);        // column w-1
  bool c3ok = (w <= 125);     // column w+2

  float part0[5] = {0.f,0.f,0.f,0.f,0.f};
  float part1[5] = {0.f,0.f,0.f,0.f,0.f};
  #pragma unroll 1
  for (int cc=0;cc<6;++cc){
    const int c = cg*8 + cc*64;
    float acc0[8], acc1[8];
    {
      f8 bias = *(const f8*)&dwb[c];
      #pragma unroll
      for (int j=0;j<8;++j){ acc0[j] = bias[j]; acc1[j] = bias[j]; }
    }
    #pragma unroll
    for (int kh=0;kh<3;++kh){
      if (!hok[kh]) continue;
      us8 cv[4];
      {
        const unsigned short* rr = &hid[(size_t)(m + (kh-1)*128)*CH + c];
        us8 z = {0,0,0,0,0,0,0,0};
        cv[0] = c0ok ? *(const us8*)(rr - CH)   : z;
        cv[1] = *(const us8*)rr;
        cv[2] = *(const us8*)(rr + CH);         // w+1 always < 128
        cv[3] = c3ok ? *(const us8*)(rr + 2*CH) : z;
      }
      #pragma unroll
      for (int kw=0;kw<3;++kw){
        f8 wf = *(const f8*)&wt_t[(kh*3+kw)*CH + c];
        #pragma unroll
        for (int j=0;j<8;++j){
          acc0[j] = fmaf(b2f(cv[kw  ][j]), wf[j], acc0[j]);
          acc1[j] = fmaf(b2f(cv[kw+1][j]), wf[j], acc1[j]);
        }
      }
    }
    us8 ov0, ov1;
    float g0[8], g1[8];
    #pragma unroll
    for (int j=0;j<8;++j){
      float a0 = acc0[j];
      float t0 = __expf(-a0*(1.5957691216f + 0.0713548996f*a0*a0));
      g0[j] = a0*__builtin_amdgcn_rcpf(1.f + t0);
      ov0[j] = f2b(g0[j]);
      float a1 = acc1[j];
      float t1 = __expf(-a1*(1.5957691216f + 0.0713548996f*a1*a1));
      g1[j] = a1*__builtin_amdgcn_rcpf(1.f + t1);
      ov1[j] = f2b(g1[j]);
    }
    *(us8*)&hid2[(size_t)m*CH + c]     = ov0;
    *(us8*)&hid2[(size_t)(m+1)*CH + c] = ov1;
    #pragma unroll
    for (int s=0;s<5;++s){
      f8 gw = *(const f8*)&gww[s*CH + c];
      #pragma unroll
      for (int j=0;j<8;++j){
        part0[s] = fmaf(g0[j], gw[j], part0[s]);
        part1[s] = fmaf(g1[j], gw[j], part1[s]);
      }
    }
  }
  #pragma unroll
  for (int s=0;s<5;++s){
    float v0 = part0[s];
    v0 += __shfl_xor(v0, 1, 64);
    v0 += __shfl_xor(v0, 2, 64);
    v0 += __shfl_xor(v0, 4, 64);
    part0[s] = v0;
    float v1 = part1[s];
    v1 += __shfl_xor(v1, 1, 64);
    v1 += __shfl_xor(v1, 2, 64);
    v1 += __shfl_xor(v1, 4, 64);
    part1[s] = v1;
  }
  if (cg==0){
    float l0[5], l1[5];
    #pragma unroll
    for (int s=0;s<5;++s){ l0[s] = part0[s] + gwb[s]; l1[s] = part1[s] + gwb[s]; }
    float mx0 = fmaxf(fmaxf(fmaxf(l0[0],l0[1]),fmaxf(l0[2],l0[3])),l0[4]);
    float mx1 = fmaxf(fmaxf(fmaxf(l1[0],l1[1]),fmaxf(l1[2],l1[3])),l1[4]);
    float s0=0.f, s1=0.f;
    #pragma unroll
    for (int s=0;s<5;++s){
      l0[s]=__expf(l0[s]-mx0); s0+=l0[s];
      l1[s]=__expf(l1[s]-mx1); s1+=l1[s];
    }
    float i0 = 1.f/s0, i1 = 1.f/s1;
    #pragma unroll
    for (int s=0;s<5;++s){
      ww[(size_t)s*Mloc + m]     = l0[s]*i0;
      ww[(size_t)s*Mloc + m + 1] = l1[s]*i1;
    }
  }
}

// ---------------- K4: PURE fc2 GEMM via bf16 MFMA: y = hid2 @ fc2w (bf16) -----
__global__ __launch_bounds__(256) void k_fc2(const unsigned short* __restrict__ hid2,
    const unsigned short* __restrict__ Bp, unsigned short* __restrict__ y,
    int Mloc){
  __shared__ unsigned short As[64][392];   // 50176 B
  const int tid = threadIdx.x;
  const int m0 = blockIdx.x*64;
  {
    const int sr = tid>>2, sq = tid&3;
    const unsigned short* src = &hid2[(size_t)(m0+sr)*CH + sq*96];
    #pragma unroll
    for (int cc=0;cc<12;++cc)
      *(us8*)&As[sr][sq*96 + cc*8] = *(const us8*)&src[cc*8];
  }
  __syncthreads();

  const int wv = tid>>6, l = tid&63;
  const int row16 = l&15, g = l>>4;
  f4v acc[6];
  #pragma unroll
  for (int nt=0;nt<6;++nt) acc[nt] = (f4v){0.f,0.f,0.f,0.f};

  #pragma unroll
  for (int ks=0;ks<12;++ks){
    s8v a = *(const s8v*)&As[wv*16 + row16][ks*32 + g*8];
    #pragma unroll
    for (int nt=0;nt<6;++nt){
      s8v b = *(const s8v*)&Bp[((size_t)(nt*12+ks)*64 + l)*8];
      acc[nt] = __builtin_amdgcn_mfma_f32_16x16x32_bf16(a, b, acc[nt], 0, 0, 0);
    }
  }

  #pragma unroll
  for (int nt=0;nt<6;++nt){
    #pragma unroll
    for (int r=0;r<4;++r){
      size_t m = (size_t)(m0 + wv*16 + g*4 + r);
      y[m*96 + nt*16 + row16] = f2b(acc[nt][r]);
    }
  }
}

// ---------------- K5: W-shift blend: out[m] = sum_i ww[i][m]*y[m-(i-2)] + b ---
__global__ __launch_bounds__(256) void k_blend(const unsigned short* __restrict__ y,
    const float* __restrict__ ww, const float* __restrict__ fc2b,
    float* __restrict__ out, int base, int Mloc){
  const int tid = threadIdx.x;
  const int m0 = blockIdx.x*64;
  const int tl = tid>>2, q = tid&3;   // token, 24-col quarter
  const int ml = m0 + tl;
  const int gm = base + ml;
  const int wp = gm & 127;
  float swgt[5];
  #pragma unroll
  for (int i=0;i<5;++i){
    int w2 = wp - (i-2);
    swgt[i] = ((unsigned)w2 < 128u) ? ww[(size_t)i*Mloc + ml] : 0.f;
  }
  const int c0 = q*24;
  float acc[24];
  #pragma unroll
  for (int j=0;j<24;++j) acc[j] = fc2b[c0+j];
  #pragma unroll
  for (int i=0;i<5;++i){
    if (swgt[i] != 0.f){
      const unsigned short* yr = &y[(size_t)(ml-(i-2))*96 + c0];
      #pragma unroll
      for (int p=0;p<3;++p){
        us8 v = *(const us8*)&yr[p*8];
        #pragma unroll
        for (int j=0;j<8;++j) acc[p*8+j] = fmaf(swgt[i], b2f(v[j]), acc[p*8+j]);
      }
    }
  }
  float* o = &out[(size_t)gm*96 + c0];
  #pragma unroll
  for (int p=0;p<6;++p)
    *(float4*)&o[p*4] = make_float4(acc[p*4],acc[p*4+1],acc[p*4+2],acc[p*4+3]);
}

extern "C" void kernel_launch(void* const* d_in, const int* in_sizes, int n_in,
                              void* d_out, int out_size, void* d_ws, size_t ws_size,
                              hipStream_t stream) {
  const float* x     = (const float*)d_in[0];
  const float* fc1_w = (const float*)d_in[3];
  const float* fc1_b = (const float*)d_in[4];
  const float* dw_w  = (const float*)d_in[5];
  const float* dw_b  = (const float*)d_in[6];
  const float* fc2_w = (const float*)d_in[7];
  const float* fc2_b = (const float*)d_in[8];
  const float* gh_w  = (const float*)d_in[9];
  const float* gh_b  = (const float*)d_in[10];
  const float* gw_w  = (const float*)d_in[11];
  const float* gw_b  = (const float*)d_in[12];
  float* out = (float*)d_out;

  // ws: wt_t 13824 B | Bp2 73728 B | Bp1 73728 B | chunk scratch
  float* wt_t = (float*)d_ws;
  unsigned short* Bp  = (unsigned short*)((char*)d_ws + 13824);
  unsigned short* Bp1 = (unsigned short*)((char*)d_ws + 13824 + 73728);
  char*  wsc  = (char*)d_ws + 13824 + 73728 + 73728;
  size_t ws_rem = (ws_size > 161280) ? ws_size - 161280 : 0;

  k_wprep<<<(9*CH + 63)/64, 64, 0, stream>>>(dw_w, wt_t);
  k_wprep2<<<144, 256, 0, stream>>>(fc2_w, Bp);
  k_wprep1<<<144, 256, 0, stream>>>(fc1_w, Bp1);

  // per-image: ww 5*Mi*4 | hid Mi*384*2 | hid2 Mi*384*2 | y Mi*96*2
  const size_t pi = (size_t)5*Mi*4 + (size_t)Mi*CH*2*2 + (size_t)Mi*96*2;
  int NI = (int)(ws_rem / pi);
  if (NI < 1) NI = 1;
  if (NI > 16) NI = 16;

  for (int b0 = 0; b0 < 16; b0 += NI) {
    int nb = (16 - b0 < NI) ? (16 - b0) : NI;
    int Mloc = nb * Mi;
    int base = b0 * Mi;
    float* ww = (float*)wsc;
    unsigned short* hid  = (unsigned short*)(ww + (size_t)5*Mloc);
    unsigned short* hid2 = hid + (size_t)Mloc*CH;
    unsigned short* yb   = hid2 + (size_t)Mloc*CH;   // Mloc*96 bf16
    k_fc1f<<<Mloc/64, 320, 0, stream>>>(x, gh_w, gh_b, Bp1, fc1_b, hid, base, Mloc);
    k_dw<<<Mloc/64, 256, 0, stream>>>(hid, wt_t, dw_b, gw_w, gw_b, hid2, ww, Mloc);
    k_fc2<<<Mloc/64, 256, 0, stream>>>(hid2, Bp, yb, Mloc);
    k_blend<<<Mloc/64, 256, 0, stream>>>(yb, ww, fc2_b, out, base, Mloc);
  }
}

// Round 16
// 490.869 us; speedup vs baseline: 1.2345x; 1.2345x over previous
//
#include <hip/hip_runtime.h>
#include <cstddef>

#define Cc 96
#define CH 384
#define Mtok 262144   // B*H*W = 16*128*128
#define Mi   16384    // tokens per image

typedef unsigned short us8 __attribute__((ext_vector_type(8)));
typedef float f8 __attribute__((ext_vector_type(8)));
typedef short s8v __attribute__((ext_vector_type(8)));
typedef float f4v __attribute__((ext_vector_type(4)));

static __device__ __forceinline__ float b2f(unsigned short s){
  union { unsigned u; float f; } v; v.u = ((unsigned)s) << 16; return v.f;
}
static __device__ __forceinline__ unsigned short f2b(float f){
  union { float f; unsigned u; } v; v.f = f;
  unsigned r = v.u + 0x7fffu + ((v.u >> 16) & 1u);
  return (unsigned short)(r >> 16);
}

// ---------------- K0a: transpose dw_w [c][tap] -> wt_t [tap][c] ----------------
__global__ __launch_bounds__(64) void k_wprep(const float* __restrict__ dww,
    float* __restrict__ wt_t){
  int i = blockIdx.x*64 + threadIdx.x;   // i = tap*CH + c
  if (i < 9*CH){
    int tap = i / CH, c = i - tap*CH;
    wt_t[i] = dww[c*9 + tap];
  }
}

// ---------------- K0b: pack fc2_w [384][96] f32 -> bf16 MFMA b-frag layout ----
__global__ __launch_bounds__(256) void k_wprep2(const float* __restrict__ fc2w,
    unsigned short* __restrict__ Bp){
  int i = blockIdx.x*256 + threadIdx.x;   // < 6*12*64*8 = 36864
  int j = i & 7;
  int t = i >> 3;
  int l = t & 63;
  int u = t >> 6;          // 0..71
  int ks = u % 12, nt = u / 12;
  int k   = ks*32 + (l>>4)*8 + j;
  int col = nt*16 + (l&15);
  Bp[i] = f2b(fc2w[(size_t)k*96 + col]);
}

// ---------------- K0c: pack fc1_w [96][384] f32 -> bf16 MFMA b-frag layout ----
__global__ __launch_bounds__(256) void k_wprep1(const float* __restrict__ fc1w,
    unsigned short* __restrict__ Bp1){
  int i = blockIdx.x*256 + threadIdx.x;   // < 24*3*64*8 = 36864
  int j = i & 7;
  int t = i >> 3;
  int l = t & 63;
  int u = t >> 6;          // 0..71
  int ks = u % 3, nt = u / 3;
  int k   = ks*32 + (l>>4)*8 + j;
  int col = nt*16 + (l&15);
  Bp1[i] = f2b(fc1w[(size_t)k*CH + col]);
}

// ---------------- K2: FUSED fc1 GEMM (MFMA) + gate-H + H-shift blend -> hid ---
// Block = 320 thr (5 waves), 64 interior tokens (16 h-rows x 4 w-cols), 80-token
// tile incl +-2-row halo. N processed in 4 chunks of 96 cols: MFMA acc[6] ->
// Y-chunk in LDS -> blend -> hid. LDS 34.2 KB (A persists, Y chunked) -> 4
// blocks/CU vs r15's 2; acc 24->6 f4v cuts VGPR. Math identical to r15.
__global__ __launch_bounds__(320) void k_fc1f(const float* __restrict__ x,
    const float* __restrict__ gh_w, const float* __restrict__ gh_b,
    const unsigned short* __restrict__ Bp1, const float* __restrict__ fc1b,
    unsigned short* __restrict__ hid, int base, int Mloc){
  __shared__ unsigned short A[80][100];    // 16000 B, persists
  __shared__ unsigned short Y[80][104];    // 16640 B, per-chunk y1 tile
  __shared__ float wh_s[80][5];            // 1600 B
  const int tid = threadIdx.x;
  const int bid = (int)blockIdx.x;
  const int img  = bid >> 8;           // 256 blocks per image
  const int rem  = bid & 255;
  const int band = rem >> 5;           // 16-row band 0..7
  const int colg = rem & 31;           // 4-col group 0..31
  const int h0 = band*16;
  const int w0 = colg*4;
  const size_t lbase = (size_t)img*16384;       // token base within chunk

  // Phase 1: stage A (80 tile-tokens; halo rows outside image -> zeros) + gate-H
  {
    const int sr = tid>>2, sq = tid&3;   // sr = tile token 0..79
    const int r = sr>>2, cw = sr&3;
    const int h = h0 + r - 2;
    const bool valid = ((unsigned)h < 128u);
    float part[5] = {0.f,0.f,0.f,0.f,0.f};
    if (valid){
      const float* src = &x[((size_t)base + lbase + h*128 + w0 + cw)*Cc + sq*24];
      #pragma unroll
      for (int p=0;p<3;++p){
        float4 v0 = *(const float4*)&src[p*8];
        float4 v1 = *(const float4*)&src[p*8+4];
        us8 ov;
        ov[0]=f2b(v0.x); ov[1]=f2b(v0.y); ov[2]=f2b(v0.z); ov[3]=f2b(v0.w);
        ov[4]=f2b(v1.x); ov[5]=f2b(v1.y); ov[6]=f2b(v1.z); ov[7]=f2b(v1.w);
        *(us8*)&A[sr][sq*24 + p*8] = ov;
        #pragma unroll
        for (int s=0;s<5;++s){
          float4 g0 = *(const float4*)&gh_w[s*Cc + sq*24 + p*8];
          float4 g1 = *(const float4*)&gh_w[s*Cc + sq*24 + p*8 + 4];
          part[s]=fmaf(v0.x,g0.x,part[s]); part[s]=fmaf(v0.y,g0.y,part[s]);
          part[s]=fmaf(v0.z,g0.z,part[s]); part[s]=fmaf(v0.w,g0.w,part[s]);
          part[s]=fmaf(v1.x,g1.x,part[s]); part[s]=fmaf(v1.y,g1.y,part[s]);
          part[s]=fmaf(v1.z,g1.z,part[s]); part[s]=fmaf(v1.w,g1.w,part[s]);
        }
      }
    } else {
      us8 z = {0,0,0,0,0,0,0,0};
      #pragma unroll
      for (int p=0;p<3;++p) *(us8*)&A[sr][sq*24 + p*8] = z;
    }
    #pragma unroll
    for (int s=0;s<5;++s){
      float v = part[s];
      v += __shfl_xor(v, 1, 64);
      v += __shfl_xor(v, 2, 64);
      part[s] = v;
    }
    if (sq==0 && valid){
      float l[5];
      #pragma unroll
      for (int s=0;s<5;++s) l[s] = part[s] + gh_b[s];
      float mx = fmaxf(fmaxf(fmaxf(l[0],l[1]),fmaxf(l[2],l[3])),l[4]);
      float sum=0.f;
      #pragma unroll
      for (int s=0;s<5;++s){ l[s]=__expf(l[s]-mx); sum+=l[s]; }
      float inv=1.f/sum;
      #pragma unroll
      for (int s=0;s<5;++s) wh_s[sr][s] = l[s]*inv;
    }
  }
  __syncthreads();

  // Role constants
  const int wv = tid>>6, l = tid&63;
  const int row16 = l&15, g = l>>4;
  const int tl = tid>>2, q = tid&3;        // blend role (tid<256)
  const int it = (2 + (tl>>2))*4 + (tl&3); // tile token index (rows 2..17)
  const int hh = h0 + (tl>>2);
  float swgt[5];
  unsigned short* o = nullptr;
  if (tid < 256){
    #pragma unroll
    for (int i=0;i<5;++i){
      int h2 = hh - (i-2);
      swgt[i] = ((unsigned)h2 < 128u) ? wh_s[it][i] : 0.f;
    }
    o = &hid[(lbase + hh*128 + w0 + (tl&3))*CH];
  }

  // Chunk loop: 4 chunks x 96 cols
  #pragma unroll 1
  for (int chunk=0;chunk<4;++chunk){
    f4v acc[6];
    #pragma unroll
    for (int j=0;j<6;++j) acc[j] = (f4v){0.f,0.f,0.f,0.f};
    #pragma unroll
    for (int ks=0;ks<3;++ks){
      s8v a = *(const s8v*)&A[wv*16 + row16][ks*32 + g*8];
      #pragma unroll
      for (int j=0;j<6;++j){
        s8v b = *(const s8v*)&Bp1[((size_t)((chunk*6+j)*3+ks)*64 + l)*8];
        acc[j] = __builtin_amdgcn_mfma_f32_16x16x32_bf16(a, b, acc[j], 0, 0, 0);
      }
    }
    __syncthreads();   // prior blend done reading Y
    #pragma unroll
    for (int j=0;j<6;++j){
      #pragma unroll
      for (int r=0;r<4;++r){
        Y[wv*16 + g*4 + r][j*16 + row16] = f2b(acc[j][r]);
      }
    }
    __syncthreads();
    if (tid < 256){
      const int c0 = chunk*96 + q*24;
      float acc2[24];
      #pragma unroll
      for (int j=0;j<24;++j) acc2[j] = fc1b[c0+j];
      #pragma unroll
      for (int i=0;i<5;++i){
        if (swgt[i] != 0.f){
          const unsigned short* yr = &Y[it - 4*(i-2)][q*24];
          #pragma unroll
          for (int p=0;p<3;++p){
            us8 v = *(const us8*)&yr[p*8];
            #pragma unroll
            for (int j=0;j<8;++j) acc2[p*8+j] = fmaf(swgt[i], b2f(v[j]), acc2[p*8+j]);
          }
        }
      }
      #pragma unroll
      for (int p=0;p<3;++p){
        us8 ov;
        #pragma unroll
        for (int j=0;j<8;++j) ov[j] = f2b(acc2[p*8+j]);
        *(us8*)&o[c0 + p*8] = ov;
      }
    }
  }
}

// ---------------- K3: dwconv3x3 + bias + fast GELU + gate-W -> hid2, ww -------
// 256 thr = 32 token-PAIRS x 8 ch-groups (2 tokens/thread), halo-shared loads.
__global__ __launch_bounds__(256) void k_dw(const unsigned short* __restrict__ hid,
    const float* __restrict__ wt_t, const float* __restrict__ dwb,
    const float* __restrict__ gww, const float* __restrict__ gwb,
    unsigned short* __restrict__ hid2, float* __restrict__ ww, int Mloc){
  const int tid = threadIdx.x;
  const int m0 = blockIdx.x*64;
  const int p  = tid>>3, cg = tid&7;
  const int m  = m0 + 2*p;                // tokens m, m+1 (same h row)
  const int h = (m>>7)&127, w = m&127;
  bool hok[3];
  #pragma unroll
  for (int k=0;k<3;++k) hok[k] = ((unsigned)(h+k-1) < 128u);
  bool c0ok = (w > 0);        // column w-1
  bool c3ok = (w <= 125);     // column w+2

  float part0[5] = {0.f,0.f,0.f,0.f,0.f};
  float part1[5] = {0.f,0.f,0.f,0.f,0.f};
  #pragma unroll 1
  for (int cc=0;cc<6;++cc){
    const int c = cg*8 + cc*64;
    float acc0[8], acc1[8];
    {
      f8 bias = *(const f8*)&dwb[c];
      #pragma unroll
      for (int j=0;j<8;++j){ acc0[j] = bias[j]; acc1[j] = bias[j]; }
    }
    #pragma unroll
    for (int kh=0;kh<3;++kh){
      if (!hok[kh]) continue;
      us8 cv[4];
      {
        const unsigned short* rr = &hid[(size_t)(m + (kh-1)*128)*CH + c];
        us8 z = {0,0,0,0,0,0,0,0};
        cv[0] = c0ok ? *(const us8*)(rr - CH)   : z;
        cv[1] = *(const us8*)rr;
        cv[2] = *(const us8*)(rr + CH);         // w+1 always < 128
        cv[3] = c3ok ? *(const us8*)(rr + 2*CH) : z;
      }
      #pragma unroll
      for (int kw=0;kw<3;++kw){
        f8 wf = *(const f8*)&wt_t[(kh*3+kw)*CH + c];
        #pragma unroll
        for (int j=0;j<8;++j){
          acc0[j] = fmaf(b2f(cv[kw  ][j]), wf[j], acc0[j]);
          acc1[j] = fmaf(b2f(cv[kw+1][j]), wf[j], acc1[j]);
        }
      }
    }
    us8 ov0, ov1;
    float g0[8], g1[8];
    #pragma unroll
    for (int j=0;j<8;++j){
      float a0 = acc0[j];
      float t0 = __expf(-a0*(1.5957691216f + 0.0713548996f*a0*a0));
      g0[j] = a0*__builtin_amdgcn_rcpf(1.f + t0);
      ov0[j] = f2b(g0[j]);
      float a1 = acc1[j];
      float t1 = __expf(-a1*(1.5957691216f + 0.0713548996f*a1*a1));
      g1[j] = a1*__builtin_amdgcn_rcpf(1.f + t1);
      ov1[j] = f2b(g1[j]);
    }
    *(us8*)&hid2[(size_t)m*CH + c]     = ov0;
    *(us8*)&hid2[(size_t)(m+1)*CH + c] = ov1;
    #pragma unroll
    for (int s=0;s<5;++s){
      f8 gw = *(const f8*)&gww[s*CH + c];
      #pragma unroll
      for (int j=0;j<8;++j){
        part0[s] = fmaf(g0[j], gw[j], part0[s]);
        part1[s] = fmaf(g1[j], gw[j], part1[s]);
      }
    }
  }
  #pragma unroll
  for (int s=0;s<5;++s){
    float v0 = part0[s];
    v0 += __shfl_xor(v0, 1, 64);
    v0 += __shfl_xor(v0, 2, 64);
    v0 += __shfl_xor(v0, 4, 64);
    part0[s] = v0;
    float v1 = part1[s];
    v1 += __shfl_xor(v1, 1, 64);
    v1 += __shfl_xor(v1, 2, 64);
    v1 += __shfl_xor(v1, 4, 64);
    part1[s] = v1;
  }
  if (cg==0){
    float l0[5], l1[5];
    #pragma unroll
    for (int s=0;s<5;++s){ l0[s] = part0[s] + gwb[s]; l1[s] = part1[s] + gwb[s]; }
    float mx0 = fmaxf(fmaxf(fmaxf(l0[0],l0[1]),fmaxf(l0[2],l0[3])),l0[4]);
    float mx1 = fmaxf(fmaxf(fmaxf(l1[0],l1[1]),fmaxf(l1[2],l1[3])),l1[4]);
    float s0=0.f, s1=0.f;
    #pragma unroll
    for (int s=0;s<5;++s){
      l0[s]=__expf(l0[s]-mx0); s0+=l0[s];
      l1[s]=__expf(l1[s]-mx1); s1+=l1[s];
    }
    float i0 = 1.f/s0, i1 = 1.f/s1;
    #pragma unroll
    for (int s=0;s<5;++s){
      ww[(size_t)s*Mloc + m]     = l0[s]*i0;
      ww[(size_t)s*Mloc + m + 1] = l1[s]*i1;
    }
  }
}

// ---------------- K4: PURE fc2 GEMM via bf16 MFMA: y = hid2 @ fc2w (bf16) -----
__global__ __launch_bounds__(256) void k_fc2(const unsigned short* __restrict__ hid2,
    const unsigned short* __restrict__ Bp, unsigned short* __restrict__ y,
    int Mloc){
  __shared__ unsigned short As[64][392];   // 50176 B
  const int tid = threadIdx.x;
  const int m0 = blockIdx.x*64;
  {
    const int sr = tid>>2, sq = tid&3;
    const unsigned short* src = &hid2[(size_t)(m0+sr)*CH + sq*96];
    #pragma unroll
    for (int cc=0;cc<12;++cc)
      *(us8*)&As[sr][sq*96 + cc*8] = *(const us8*)&src[cc*8];
  }
  __syncthreads();

  const int wv = tid>>6, l = tid&63;
  const int row16 = l&15, g = l>>4;
  f4v acc[6];
  #pragma unroll
  for (int nt=0;nt<6;++nt) acc[nt] = (f4v){0.f,0.f,0.f,0.f};

  #pragma unroll
  for (int ks=0;ks<12;++ks){
    s8v a = *(const s8v*)&As[wv*16 + row16][ks*32 + g*8];
    #pragma unroll
    for (int nt=0;nt<6;++nt){
      s8v b = *(const s8v*)&Bp[((size_t)(nt*12+ks)*64 + l)*8];
      acc[nt] = __builtin_amdgcn_mfma_f32_16x16x32_bf16(a, b, acc[nt], 0, 0, 0);
    }
  }

  #pragma unroll
  for (int nt=0;nt<6;++nt){
    #pragma unroll
    for (int r=0;r<4;++r){
      size_t m = (size_t)(m0 + wv*16 + g*4 + r);
      y[m*96 + nt*16 + row16] = f2b(acc[nt][r]);
    }
  }
}

// ---------------- K5: W-shift blend: out[m] = sum_i ww[i][m]*y[m-(i-2)] + b ---
__global__ __launch_bounds__(256) void k_blend(const unsigned short* __restrict__ y,
    const float* __restrict__ ww, const float* __restrict__ fc2b,
    float* __restrict__ out, int base, int Mloc){
  const int tid = threadIdx.x;
  const int m0 = blockIdx.x*64;
  const int tl = tid>>2, q = tid&3;   // token, 24-col quarter
  const int ml = m0 + tl;
  const int gm = base + ml;
  const int wp = gm & 127;
  float swgt[5];
  #pragma unroll
  for (int i=0;i<5;++i){
    int w2 = wp - (i-2);
    swgt[i] = ((unsigned)w2 < 128u) ? ww[(size_t)i*Mloc + ml] : 0.f;
  }
  const int c0 = q*24;
  float acc[24];
  #pragma unroll
  for (int j=0;j<24;++j) acc[j] = fc2b[c0+j];
  #pragma unroll
  for (int i=0;i<5;++i){
    if (swgt[i] != 0.f){
      const unsigned short* yr = &y[(size_t)(ml-(i-2))*96 + c0];
      #pragma unroll
      for (int p=0;p<3;++p){
        us8 v = *(const us8*)&yr[p*8];
        #pragma unroll
        for (int j=0;j<8;++j) acc[p*8+j] = fmaf(swgt[i], b2f(v[j]), acc[p*8+j]);
      }
    }
  }
  float* o = &out[(size_t)gm*96 + c0];
  #pragma unroll
  for (int p=0;p<6;++p)
    *(float4*)&o[p*4] = make_float4(acc[p*4],acc[p*4+1],acc[p*4+2],acc[p*4+3]);
}

extern "C" void kernel_launch(void* const* d_in, const int* in_sizes, int n_in,
                              void* d_out, int out_size, void* d_ws, size_t ws_size,
                              hipStream_t stream) {
  const float* x     = (const float*)d_in[0];
  const float* fc1_w = (const float*)d_in[3];
  const float* fc1_b = (const float*)d_in[4];
  const float* dw_w  = (const float*)d_in[5];
  const float* dw_b  = (const float*)d_in[6];
  const float* fc2_w = (const float*)d_in[7];
  const float* fc2_b = (const float*)d_in[8];
  const float* gh_w  = (const float*)d_in[9];
  const float* gh_b  = (const float*)d_in[10];
  const float* gw_w  = (const float*)d_in[11];
  const float* gw_b  = (const float*)d_in[12];
  float* out = (float*)d_out;

  // ws: wt_t 13824 B | Bp2 73728 B | Bp1 73728 B | chunk scratch
  float* wt_t = (float*)d_ws;
  unsigned short* Bp  = (unsigned short*)((char*)d_ws + 13824);
  unsigned short* Bp1 = (unsigned short*)((char*)d_ws + 13824 + 73728);
  char*  wsc  = (char*)d_ws + 13824 + 73728 + 73728;
  size_t ws_rem = (ws_size > 161280) ? ws_size - 161280 : 0;

  k_wprep<<<(9*CH + 63)/64, 64, 0, stream>>>(dw_w, wt_t);
  k_wprep2<<<144, 256, 0, stream>>>(fc2_w, Bp);
  k_wprep1<<<144, 256, 0, stream>>>(fc1_w, Bp1);

  // per-image: ww 5*Mi*4 | hid Mi*384*2 | hid2 Mi*384*2 | y Mi*96*2
  const size_t pi = (size_t)5*Mi*4 + (size_t)Mi*CH*2*2 + (size_t)Mi*96*2;
  int NI = (int)(ws_rem / pi);
  if (NI < 1) NI = 1;
  if (NI > 16) NI = 16;

  for (int b0 = 0; b0 < 16; b0 += NI) {
    int nb = (16 - b0 < NI) ? (16 - b0) : NI;
    int Mloc = nb * Mi;
    int base = b0 * Mi;
    float* ww = (float*)wsc;
    unsigned short* hid  = (unsigned short*)(ww + (size_t)5*Mloc);
    unsigned short* hid2 = hid + (size_t)Mloc*CH;
    unsigned short* yb   = hid2 + (size_t)Mloc*CH;   // Mloc*96 bf16
    k_fc1f<<<Mloc/64, 320, 0, stream>>>(x, gh_w, gh_b, Bp1, fc1_b, hid, base, Mloc);
    k_dw<<<Mloc/64, 256, 0, stream>>>(hid, wt_t, dw_b, gw_w, gw_b, hid2, ww, Mloc);
    k_fc2<<<Mloc/64, 256, 0, stream>>>(hid2, Bp, yb, Mloc);
    k_blend<<<Mloc/64, 256, 0, stream>>>(yb, ww, fc2_b, out, base, Mloc);
  }
}